// Round 4
// baseline (8954.150 us; speedup 1.0000x reference)
//
#include <hip/hip_runtime.h>
#include <hip/hip_bf16.h>
#include <cstdint>

// ---------------------------------------------------------------------------
// 2-layer LSTM (B=512, T=128, F=64, H=1024) + dense sigmoid head.
// fp16 MFMA GEMMs w/ fp32 accumulation, fused gate epilogue.
// R4: LDS-FREE step kernel. MFMA fragments are loaded directly from
// row-major global memory (A: h/x rows; B: pre-transposed weight rows) into
// VGPRs — no __shared__, no __syncthreads, no vmcnt(0) barrier drains.
// Explicit register double-buffer (12 fragment loads in flight for k-tile
// kt+1 while MFMAs consume kt) lets the compiler emit fine-grained
// s_waitcnt vmcnt(N) — the AITER-style pipeline the LDS structure forbids.
// ---------------------------------------------------------------------------

typedef __attribute__((ext_vector_type(8))) _Float16 half8;
typedef __attribute__((ext_vector_type(4))) _Float16 half4v;
typedef __attribute__((ext_vector_type(4))) float    float4v;

__device__ __forceinline__ float sigf(float x) { return 1.0f / (1.0f + __expf(-x)); }
__device__ __forceinline__ float tanhfast(float x) { return 2.0f * sigf(2.0f * x) - 1.0f; }

static constexpr size_t HS = 512ull * 1024;   // one h ping-pong slot (elems)

struct Frags {            // one k-tile (BK=64) of fragments for one wave
    half8 a0[2];          // A subtile m..m+15, per K0
    half8 a1[2];          // A subtile m+16..m+31
    half8 b[2][4];        // B per K0 per gate
};

// ---------------------------------------------------------------------------
// Fused pipeline step. Launch s (0..128):
//   blocks [0,256):   layer1 step t=s      (skip when s==128)
//   blocks [256,512): layer2 step t=s-1    (skip when s==0)
// z = [A1|A2] @ [B1T|B2T]^T + bias ; gates ; c,h update.
// Block: 4 waves, tile 64m x 32n x 4 gates. Wave: 32m x 16n x 4 gates.
// Grid 512 = 2 blocks/CU (one per role), 2 waves/SIMD.
// Fragment loads: lane l reads 16 B at row (base + (l&15)), col K0*32+(l>>4)*8
// -> 16 x 64 B segments per instr, full 128 B line use across K0=0,1.
// Intra-CU duplicate fragment reads (waves sharing mh/nh) hit L1.
// ---------------------------------------------------------------------------
__global__ __launch_bounds__(256, 2) void fused_step(
    int s,
    const _Float16* __restrict__ xb,
    const _Float16* __restrict__ W1T, const _Float16* __restrict__ U1T,
    const float* __restrict__ b1, float* __restrict__ c1, _Float16* __restrict__ h1,
    const _Float16* __restrict__ W2T, const _Float16* __restrict__ U2T,
    const float* __restrict__ b2, float* __restrict__ c2, _Float16* __restrict__ h2)
{
    const int role = blockIdx.x >> 8;        // 0: layer1, 1: layer2
    const int idx  = blockIdx.x & 255;       // (m-tile, n-tile)

    const _Float16 *A1, *A2, *B1T, *B2T;
    const float* bias; float* cs; _Float16* ho;
    long a1s, a1o; int KA, ldb1;
    if (role == 0) {                         // ---- layer 1, step t = s ----
        const int t = s; if (t >= 128) return;
        A1 = xb; a1s = 128 * 64; a1o = (long)t * 64; KA = 64;
        B1T = W1T; ldb1 = 64;
        A2 = h1 + (size_t)(t & 1) * HS;      // h1(t-1)
        B2T = U1T; bias = b1; cs = c1;
        ho = h1 + (size_t)(1 - (t & 1)) * HS;
    } else {                                 // ---- layer 2, step t = s-1 ----
        const int t = s - 1; if (t < 0) return;
        A1 = h1 + (size_t)(1 - (t & 1)) * HS;  // h1(t), written by launch s-1
        a1s = 1024; a1o = 0; KA = 1024;
        B1T = W2T; ldb1 = 1024;
        A2 = h2 + (size_t)(t & 1) * HS;      // h2(t-1)
        B2T = U2T; bias = b2; cs = c2;
        ho = h2 + (size_t)(1 - (t & 1)) * HS;
    }

    const int tid = threadIdx.x;
    const int w   = tid >> 6;      // wave 0..3
    const int l   = tid & 63;
    const int q   = l >> 4;        // quad 0..3 (k-chunk within K0)
    const int c16 = l & 15;
    const int mh  = w & 1;         // 32-row half
    const int nh  = w >> 1;        // 16-unit half

    const int m0 = (idx >> 5) * 64;      // 8 m-tiles
    const int n0 = (idx & 31) * 32;      // 32 n-tiles (low bits -> XCD slice)

    const int  ma   = m0 + mh * 32 + c16;        // A fragment row (subtile 0)
    const long nrow = n0 + nh * 16 + c16;        // B fragment row (gate 0)
    const int  q8   = q * 8;

    float4v acc[4][2] = {};        // [gate][m-subtile]
    const int KT = (KA + 1024) >> 6;   // BK=64: 17 k-tiles (L1) / 32 (L2)

    auto load_frags = [&](int kt, Frags& f) {
        const int kbase = kt << 6;
        const _Float16* Ap; long arow, aoff;
        const _Float16* Bp; long ldb,  bcol;
        if (kbase < KA) { Ap = A1; arow = a1s;  aoff = a1o + kbase;
                          Bp = B1T; ldb = ldb1; bcol = kbase; }
        else            { Ap = A2; arow = 1024; aoff = kbase - KA;
                          Bp = B2T; ldb = 1024; bcol = kbase - KA; }
        const _Float16* a0p = Ap + (long)ma * arow + aoff + q8;
        const _Float16* a1p = a0p + 16 * arow;
        const _Float16* bp  = Bp + nrow * ldb + bcol + q8;
        const long gs = (long)1024 * ldb;        // gate stride in B rows
#pragma unroll
        for (int K0 = 0; K0 < 2; ++K0) {
            f.a0[K0] = *(const half8*)(a0p + K0 * 32);
            f.a1[K0] = *(const half8*)(a1p + K0 * 32);
#pragma unroll
            for (int g = 0; g < 4; ++g)
                f.b[K0][g] = *(const half8*)(bp + g * gs + K0 * 32);
        }
    };
    auto compute = [&](const Frags& f) {
#pragma unroll
        for (int K0 = 0; K0 < 2; ++K0) {
#pragma unroll
            for (int g = 0; g < 4; ++g) {
                acc[g][0] = __builtin_amdgcn_mfma_f32_16x16x32_f16(f.a0[K0], f.b[K0][g], acc[g][0], 0, 0, 0);
                acc[g][1] = __builtin_amdgcn_mfma_f32_16x16x32_f16(f.a1[K0], f.b[K0][g], acc[g][1], 0, 0, 0);
            }
        }
    };

    // register double-buffered K-loop: loads for kt+1 in flight over MFMAs(kt)
    Frags f0, f1;
    load_frags(0, f0);
    int kt = 0;
    for (; kt + 2 <= KT; kt += 2) {
        load_frags(kt + 1, f1);
        compute(f0);
        if (kt + 2 < KT) load_frags(kt + 2, f0);
        compute(f1);
    }
    if (kt < KT) compute(f0);      // odd KT tail (layer1: KT=17)

    // ---- fused gate epilogue: D row = quad*4+i, col = lane&15 ----
    const int ng = n0 + nh * 16 + c16;
    const float bi  = bias[ng];
    const float bff = bias[1024 + ng];
    const float bg  = bias[2048 + ng];
    const float bo  = bias[3072 + ng];
#pragma unroll
    for (int mt = 0; mt < 2; ++mt) {
#pragma unroll
        for (int i = 0; i < 4; ++i) {
            const int m = m0 + mh * 32 + mt * 16 + q * 4 + i;
            const float zi = acc[0][mt][i] + bi;
            const float zf = acc[1][mt][i] + bff;
            const float zg = acc[2][mt][i] + bg;
            const float zo = acc[3][mt][i] + bo;
            const float ig = sigf(zi);
            const float fg = sigf(zf);
            const float gg = tanhfast(zg);
            const float og = sigf(zo);
            const size_t id2 = (size_t)m * 1024 + ng;
            const float cc = fg * cs[id2] + ig * gg;
            cs[id2] = cc;
            ho[id2] = (_Float16)(og * tanhfast(cc));
        }
    }
}

// ---------------------------------------------------------------------------
// fp32 (R,C) -> f16 (C,R) tiled transpose-convert
// ---------------------------------------------------------------------------
__global__ void transpose_cvt(const float* __restrict__ in, _Float16* __restrict__ out,
                              int R, int C)
{
    __shared__ float tile[32][33];
    const int c0 = blockIdx.x * 32, r0 = blockIdx.y * 32;
    const int tx = threadIdx.x, ty = threadIdx.y;   // (32, 8)
#pragma unroll
    for (int j = ty; j < 32; j += 8) {
        int r = r0 + j, c = c0 + tx;
        tile[j][tx] = (r < R && c < C) ? in[(size_t)r * C + c] : 0.0f;
    }
    __syncthreads();
#pragma unroll
    for (int j = ty; j < 32; j += 8) {
        int c = c0 + j, r = r0 + tx;
        if (c < C && r < R) out[(size_t)c * R + r] = (_Float16)tile[tx][j];
    }
}

__global__ void cvt_f16(const float* __restrict__ in, _Float16* __restrict__ out, int n)
{
    int i = (blockIdx.x * blockDim.x + threadIdx.x) * 4;
    if (i + 3 < n) {
        float4 v = *(const float4*)(in + i);
        half4v h = { (_Float16)v.x, (_Float16)v.y, (_Float16)v.z, (_Float16)v.w };
        *(half4v*)(out + i) = h;
    }
}

// ---------------------------------------------------------------------------
// Dense head: out[m] = sigmoid(h2[m,:] . Wd + bd), one wave per row
// ---------------------------------------------------------------------------
__global__ __launch_bounds__(64) void dense_head(const _Float16* __restrict__ h2,
                                                 const float* __restrict__ Wd,
                                                 const float* __restrict__ bd,
                                                 float* __restrict__ out)
{
    const int m = blockIdx.x;
    const int l = threadIdx.x;
    float s = 0.0f;
#pragma unroll
    for (int k = l; k < 1024; k += 64)
        s += (float)h2[(size_t)m * 1024 + k] * Wd[k];
    for (int off = 32; off > 0; off >>= 1) s += __shfl_down(s, off);
    if (l == 0) out[m] = 1.0f / (1.0f + __expf(-(s + bd[0])));
}

// ---------------------------------------------------------------------------

extern "C" void kernel_launch(void* const* d_in, const int* in_sizes, int n_in,
                              void* d_out, int out_size, void* d_ws, size_t ws_size,
                              hipStream_t stream)
{
    const float* x  = (const float*)d_in[0];
    const float* W1 = (const float*)d_in[1];
    const float* U1 = (const float*)d_in[2];
    const float* b1 = (const float*)d_in[3];
    const float* W2 = (const float*)d_in[4];
    const float* U2 = (const float*)d_in[5];
    const float* b2 = (const float*)d_in[6];
    const float* Wd = (const float*)d_in[7];
    const float* bd = (const float*)d_in[8];
    float* out = (float*)d_out;

    char* ws = (char*)d_ws;
    size_t off = 0;
    auto alloc = [&](size_t bytes) {
        char* p = ws + off;
        off = (off + bytes + 255) & ~(size_t)255;
        return p;
    };
    _Float16* xb  = (_Float16*)alloc(512ull * 128 * 64 * 2);   // x as f16 (B,T,F)
    _Float16* W1T = (_Float16*)alloc(4096ull * 64 * 2);        // (4H, F)
    _Float16* U1T = (_Float16*)alloc(4096ull * 1024 * 2);      // (4H, H)
    _Float16* W2T = (_Float16*)alloc(4096ull * 1024 * 2);
    _Float16* U2T = (_Float16*)alloc(4096ull * 1024 * 2);
    _Float16* h1  = (_Float16*)alloc(2ull * 512 * 1024 * 2);   // ping-pong
    _Float16* h2  = (_Float16*)alloc(2ull * 512 * 1024 * 2);
    float*    c1  = (float*)alloc(512ull * 1024 * 4);
    float*    c2  = (float*)alloc(512ull * 1024 * 4);

    // zero initial state (ws is re-poisoned to 0xAA before every launch)
    hipMemsetAsync(c1, 0, 512ull * 1024 * 4, stream);
    hipMemsetAsync(c2, 0, 512ull * 1024 * 4, stream);
    hipMemsetAsync(h1, 0, 512ull * 1024 * 2, stream);  // slot 0 (read at t=0)
    hipMemsetAsync(h2, 0, 512ull * 1024 * 2, stream);  // slot 0

    cvt_f16<<<4096, 256, 0, stream>>>(x, xb, 512 * 128 * 64);
    dim3 tb(32, 8);
    transpose_cvt<<<dim3(4096 / 32,   64 / 32), tb, 0, stream>>>(W1, W1T,   64, 4096);
    transpose_cvt<<<dim3(4096 / 32, 1024 / 32), tb, 0, stream>>>(U1, U1T, 1024, 4096);
    transpose_cvt<<<dim3(4096 / 32, 1024 / 32), tb, 0, stream>>>(W2, W2T, 1024, 4096);
    transpose_cvt<<<dim3(4096 / 32, 1024 / 32), tb, 0, stream>>>(U2, U2T, 1024, 4096);

    // 129 pipelined launches: launch s does layer1(s) + layer2(s-1)
    for (int s = 0; s <= 128; ++s) {
        fused_step<<<512, 256, 0, stream>>>(s, xb,
                                            W1T, U1T, b1, c1, h1,
                                            W2T, U2T, b2, c2, h2);
    }
    // h2(127) lands in slot 0
    dense_head<<<512, 64, 0, stream>>>(h2, Wd, bd, out);
}